// Round 8
// baseline (218.156 us; speedup 1.0000x reference)
//
#include <hip/hip_runtime.h>

// ---------------------------------------------------------------------------
// H_DYNA: fused 24-step recurrent memory-attention GRU on MI355X (gfx950).
// R7 (recompile fix: named ZERO4 instead of braced-init macro arg):
//  - softmax row-sums via MFMA with all-ones B-frag (every lane gets the sum
//    in its C-regs) -> 32 ds_bpermute shuffle chains removed
//  - decoder head y = h@Wo via MFMA with broadcast-Wo B-frags (hi/lo split)
//  - cross-step score pipelining: partial scores for step t+1 (66 MFMAs,
//    qh[1..11] x mem[0..10]) computed mid-step; step start needs only 6 fresh
//    MFMAs (qh[11] x mem[11]) on the carried partial accumulator
// ---------------------------------------------------------------------------

typedef short short8 __attribute__((ext_vector_type(8)));   // 8 x bf16 bits
typedef float f32x4 __attribute__((ext_vector_type(4)));

#define DEV static __device__ __forceinline__

DEV unsigned short f2bf(float f) {
  union { float f; unsigned u; } v; v.f = f;
  unsigned r = v.u + 0x7FFFu + ((v.u >> 16) & 1u);   // RNE
  return (unsigned short)(r >> 16);
}
DEV float bf2f(unsigned short b) {
  union { unsigned u; float f; } v; v.u = ((unsigned)b) << 16;
  return v.f;
}
DEV unsigned cvtpk(float a, float b) {                // packed RNE f32->bf16 x2
  unsigned r;
  asm("v_cvt_pk_bf16_f32 %0, %1, %2" : "=v"(r) : "v"(a), "v"(b));
  return r;
}
DEV float rcpf(float x) { return __builtin_amdgcn_rcpf(x); }

// ---- ws layout (ushort units) ----
#define WG_OFF  36864   // mem frags: 72 frags * 512 before this
#define WQ_OFF  61440   // gate-W frags: 48 * 512 (hi/lo interleaved)
#define LM_OFF  63488   // Wq frags: 4 * 512
#define GM_OFF  65536   // lmean frags: 4 * 512
#define WS_TOT  66560   // gmean frags: 2 * 512

// ---- LDS layout (bytes) ----
#define L_W     0             // 48 gate-W frags (fid order), 49152 B
#define L_WQ    49152         // 4 Wq frags
#define L_LM    53248         // lmean 4 + gmean 2 frags
#define L_SCR   59392         // per-wave scratch
#define SCR_STRIDE 21504
#define SMEM_BYTES 145408     // 59392 + 4*21504

// per-wave scratch regions
#define R_AL 0
#define R_AG 2048
#define R_FU 3072
#define R_HH 5120
#define R_HL 7168
#define R_RH 9216
#define R_RL 11264
#define R_NSW 13312           // 8 KB: nsw B-frags (per-wave copy)
#define R_QQ 0                // reuse AL after its reads

#define MFMA16(a, b, c) __builtin_amdgcn_mfma_f32_16x16x32_bf16((a), (b), (c), 0, 0, 0)

// A-frag scatter address for element (row = 4g+reg via +reg*16, k = col)
DEV int scat_off(int col, int g) {
  int kp = col & 31;
  return ((col >> 5) << 10) + ((kp >> 3) << 8) + (g << 6) + ((kp & 7) << 1);
}
DEV void scat4(char* p, f32x4 v) {        // 4 C-regs -> bf16 A-layout
  unsigned p0 = cvtpk(v[0], v[1]), p1 = cvtpk(v[2], v[3]);
  *(unsigned short*)(p)      = (unsigned short)p0;
  *(unsigned short*)(p + 16) = (unsigned short)(p0 >> 16);
  *(unsigned short*)(p + 32) = (unsigned short)p1;
  *(unsigned short*)(p + 48) = (unsigned short)(p1 >> 16);
}
DEV void scat4_hilo(char* ph, char* pl, f32x4 v) {   // hi/lo split scatter
  unsigned p0 = cvtpk(v[0], v[1]), p1 = cvtpk(v[2], v[3]);
  float h0 = __uint_as_float(p0 << 16), h1 = __uint_as_float(p0 & 0xFFFF0000u);
  float h2 = __uint_as_float(p1 << 16), h3 = __uint_as_float(p1 & 0xFFFF0000u);
  unsigned q0 = cvtpk(v[0] - h0, v[1] - h1), q1 = cvtpk(v[2] - h2, v[3] - h3);
  *(unsigned short*)(ph)      = (unsigned short)p0;
  *(unsigned short*)(ph + 16) = (unsigned short)(p0 >> 16);
  *(unsigned short*)(ph + 32) = (unsigned short)p1;
  *(unsigned short*)(ph + 48) = (unsigned short)(p1 >> 16);
  *(unsigned short*)(pl)      = (unsigned short)q0;
  *(unsigned short*)(pl + 16) = (unsigned short)(q0 >> 16);
  *(unsigned short*)(pl + 32) = (unsigned short)q1;
  *(unsigned short*)(pl + 48) = (unsigned short)(q1 >> 16);
}

// ===========================================================================
// Prep: pack memory / weight matrices into MFMA B-fragment order (bf16).
// (unchanged from R6)
// ===========================================================================
__global__ __launch_bounds__(256, 1) void dyna_prep(
    const float* __restrict__ lmem, const float* __restrict__ gmem,
    const float* __restrict__ Wq, const float* __restrict__ Wz,
    const float* __restrict__ Wr, const float* __restrict__ Wc,
    unsigned short* __restrict__ ws)
{
  int i = blockIdx.x * 256 + threadIdx.x;
  if (i >= WS_TOT) return;

  if (i < WG_OFF) {                       // score-memory frags: [s 0..11][nt 0..5]
    int f = i >> 9, r = i & 511, lane = r >> 3, j = r & 7;
    int g = lane >> 4, u = lane & 15;
    int s = f / 6, nt = f % 6;
    int m = nt * 16 + u, p = g * 8 + j;
    float v = (m < 64) ? lmem[(m * 12 + s) * 32 + p]
                       : gmem[((m - 64) * 12 + s) * 32 + p];
    ws[i] = f2bf(v);
  } else if (i < WQ_OFF) {                // gate W frags: fid=((gate*4+nt)*2+kc)*2+hl
    int t = i - WG_OFF;
    int f = t >> 9, r = t & 511, lane = r >> 3, j = r & 7;
    int g = lane >> 4, u = lane & 15;
    int hl = f & 1, kc = (f >> 1) & 1, nt = (f >> 2) & 3, gate = f >> 4;
    int k = kc * 32 + g * 8 + j, col = nt * 16 + u;
    const float* W = (gate == 0) ? Wz : (gate == 1) ? Wr : Wc;
    float w = W[(1 + k) * 64 + col];
    if (hl) { float hi = bf2f(f2bf(w)); ws[i] = f2bf(w - hi); }
    else ws[i] = f2bf(w);
  } else if (i < LM_OFF) {                // Wq frags: fid = nt*2+kc
    int t = i - WQ_OFF;
    int f = t >> 9, r = t & 511, lane = r >> 3, j = r & 7;
    int g = lane >> 4, u = lane & 15;
    int kc = f & 1, nt = f >> 1;
    int k = kc * 32 + g * 8 + j, col = nt * 16 + u;
    ws[i] = f2bf(Wq[k * 32 + col]);
  } else if (i < GM_OFF) {                // lmean frags: fid = kc*2+nt
    int t = i - LM_OFF;
    int f = t >> 9, r = t & 511, lane = r >> 3, j = r & 7;
    int g = lane >> 4, u = lane & 15;
    int kc = f >> 1, nt = f & 1;
    int k = kc * 32 + g * 8 + j, p = nt * 16 + u;
    float s = 0.f;
    for (int ss = 0; ss < 12; ++ss) s += lmem[(k * 12 + ss) * 32 + p];
    ws[i] = f2bf(s * (1.0f / 12.0f));
  } else {                                // gmean frags: fid = nt
    int t = i - GM_OFF;
    int f = t >> 9, r = t & 511, lane = r >> 3, j = r & 7;
    int g = lane >> 4, u = lane & 15;
    int nt = f;
    int k = g * 8 + j, p = nt * 16 + u;
    float s = 0.f;
    for (int ss = 0; ss < 12; ++ss) s += gmem[(k * 12 + ss) * 32 + p];
    ws[i] = f2bf(s * (1.0f / 12.0f));
  }
}

// ===========================================================================
// Main fused kernel. 256 blocks * 256 thr. Block = nodes {2B, 2B+1};
// wave w: node 2B+(w>>1), batch half (w&1), rows = hb*16 + 4g+reg.
// ===========================================================================
__global__ __launch_bounds__(256, 1) void dyna_main(
    const float* __restrict__ src, const float* __restrict__ emb,
    const float* __restrict__ pool, const float* __restrict__ bq,
    const float* __restrict__ Wz, const float* __restrict__ bz,
    const float* __restrict__ Wr, const float* __restrict__ br,
    const float* __restrict__ Wc, const float* __restrict__ bc,
    const float* __restrict__ Wo, const float* __restrict__ bo,
    const unsigned short* __restrict__ ws, float* __restrict__ out)
{
  extern __shared__ char smem[];
  const int tid = threadIdx.x;
  const int lane = tid & 63, wid = tid >> 6;
  const int g = lane >> 4, u = lane & 15;
  const int n = blockIdx.x * 2 + (wid >> 1);
  const int hb = wid & 1;
  const f32x4 ZERO4 = {0.f, 0.f, 0.f, 0.f};

  // ---- stage W (48) + Wq (4) + lm/gm (6) frags: ws is contiguous here ----
  {
    const short8* s8 = (const short8*)ws;
    short8* d8 = (short8*)smem;
    for (int i = tid; i < 3712; i += 256) d8[i] = s8[4608 + i];  // 4608 = WG_OFF/8
  }

  // ---- 72 score-memory B-frags -> registers (one-time global load) ----
  short8 marr[72];
  #pragma unroll
  for (int f = 0; f < 72; ++f)
    marr[f] = *(const short8*)(ws + (f << 9) + lane * 8);

  char* SCR = smem + L_SCR + wid * SCR_STRIDE;

  // ---- nsw[n] = emb[n] @ pool, built as B-frags, stored in per-wave LDS ----
  #pragma unroll
  for (int kc = 0; kc < 2; ++kc)
    #pragma unroll
    for (int nt = 0; nt < 4; ++nt) {
      short8 v;
      #pragma unroll
      for (int j = 0; j < 8; ++j) {
        int k = kc * 32 + g * 8 + j, col = nt * 16 + u;
        float s = 0.f;
        #pragma unroll
        for (int d = 0; d < 10; ++d)
          s += emb[n * 10 + d] * pool[(d * 64 + k) * 64 + col];
        v[j] = (short)f2bf(s);
      }
      *(short8*)(SCR + R_NSW + ((kc * 4 + nt) << 10) + (lane << 4)) = v;
    }

  // ---- special B-frags in registers: all-ones (row-sum) + broadcast Wo ----
  short8 ones, woh[2], wol[2];
  #pragma unroll
  for (int j = 0; j < 8; ++j) ones[j] = (short)0x3F80;
  #pragma unroll
  for (int kc = 0; kc < 2; ++kc)
    #pragma unroll
    for (int j = 0; j < 8; ++j) {
      float w = Wo[kc * 32 + g * 8 + j];
      unsigned short hi = f2bf(w);
      woh[kc][j] = (short)hi;
      wol[kc][j] = (short)f2bf(w - bf2f(hi));
    }

  // ---- per-lane constants ----
  float w0z[4], w0r[4], w0c[4], bzv[4], brv[4], bcv[4], bqv[2];
  #pragma unroll
  for (int nt = 0; nt < 4; ++nt) {
    int col = nt * 16 + u;
    w0z[nt] = Wz[col]; w0r[nt] = Wr[col]; w0c[nt] = Wc[col];
    bzv[nt] = bz[col]; brv[nt] = br[col]; bcv[nt] = bc[col];
  }
  bqv[0] = bq[u]; bqv[1] = bq[16 + u];
  const float bov = bo[0];

  // ---- persistent per-row state ----
  short8 qh[12];
  {
    short8 qi;
    #pragma unroll
    for (int j = 0; j < 8; ++j) qi[j] = (short)f2bf(bq[g * 8 + j]);
    #pragma unroll
    for (int s = 0; s < 12; ++s) qh[s] = qi;
  }
  f32x4 hreg[4];
  #pragma unroll
  for (int nt = 0; nt < 4; ++nt) hreg[nt] = ZERO4;
  float xreg[4] = {0.f, 0.f, 0.f, 0.f};

  // pipelined partial scores for step 0: sum over history slots 0..10
  f32x4 sacc_next[6];
  #pragma unroll
  for (int nt = 0; nt < 6; ++nt) sacc_next[nt] = ZERO4;
  #pragma unroll
  for (int s = 0; s <= 10; ++s)
    #pragma unroll
    for (int nt = 0; nt < 6; ++nt)
      sacc_next[nt] = MFMA16(qh[s], marr[s * 6 + nt], sacc_next[nt]);

  // initial h=0 hi/lo scatter (serves step 0's gate reads)
  #pragma unroll
  for (int nt = 0; nt < 4; ++nt) {
    int so = scat_off(nt * 16 + u, g);
    scat4_hilo(SCR + R_HH + so, SCR + R_HL + so, hreg[nt]);
  }

  __syncthreads();    // staged shared frags visible; the only barrier

  for (int t = 0; t < 24; ++t) {
    // ---- x input (global latency hides under score MFMAs) ----
    if (t <= 12) {
      int tt = t < 12 ? t : 11;
      #pragma unroll
      for (int reg = 0; reg < 4; ++reg) {
        int b = hb * 16 + g * 4 + reg;
        xreg[reg] = src[(b * 12 + tt) * 512 + n];
      }
    }

    // ---- h_prev frag reads issued early ----
    short8 hhi0 = *(const short8*)(SCR + R_HH + (lane << 4));
    short8 hhi1 = *(const short8*)(SCR + R_HH + 1024 + (lane << 4));
    short8 hlo0 = *(const short8*)(SCR + R_HL + (lane << 4));
    short8 hlo1 = *(const short8*)(SCR + R_HL + 1024 + (lane << 4));

    // ---- scores: carried partial + 6 fresh MFMAs (qh[11] x mem slot 11) ----
    f32x4 sacc[6];
    #pragma unroll
    for (int nt = 0; nt < 6; ++nt)
      sacc[nt] = MFMA16(qh[11], marr[66 + nt], sacc_next[nt]);

    // ---- e = exp(score); scatter unnormalized e -> AL / AG ----
    #pragma unroll
    for (int nt = 0; nt < 6; ++nt)
      #pragma unroll
      for (int reg = 0; reg < 4; ++reg)
        sacc[nt][reg] = __expf(sacc[nt][reg]);
    #pragma unroll
    for (int nt = 0; nt < 4; ++nt)
      scat4(SCR + R_AL + scat_off(nt * 16 + u, g), sacc[nt]);
    #pragma unroll
    for (int nt = 0; nt < 2; ++nt)
      scat4(SCR + R_AG + scat_off(nt * 16 + u, g), sacc[4 + nt]);

    // ---- rebuild partial for step t+1 (uses pre-shift qh[1..11]) ----
    // independent filler MFMAs: overlap with gate phase stalls
    #pragma unroll
    for (int nt = 0; nt < 6; ++nt) sacc_next[nt] = ZERO4;
    #pragma unroll
    for (int s = 1; s <= 11; ++s)
      #pragma unroll
      for (int nt = 0; nt < 6; ++nt)
        sacc_next[nt] = MFMA16(qh[s], marr[(s - 1) * 6 + nt], sacc_next[nt]);

    // ---- z, r gates: hi/lo split MFMA (W hi+lo from LDS) ----
    f32x4 zacc[4], racc[4];
    #pragma unroll
    for (int nt = 0; nt < 4; ++nt) {
      zacc[nt] = ZERO4;
      racc[nt] = ZERO4;
    }
    #pragma unroll
    for (int kc = 0; kc < 2; ++kc) {
      short8 hh = kc ? hhi1 : hhi0;
      short8 hl = kc ? hlo1 : hlo0;
      #pragma unroll
      for (int nt = 0; nt < 4; ++nt) {
        short8 wzh = *(const short8*)(smem + L_W + ((((0 + nt) * 2 + kc) * 2 + 0) << 10) + (lane << 4));
        short8 wzl = *(const short8*)(smem + L_W + ((((0 + nt) * 2 + kc) * 2 + 1) << 10) + (lane << 4));
        zacc[nt] = MFMA16(hh, wzh, zacc[nt]);
        zacc[nt] = MFMA16(hl, wzh, zacc[nt]);
        zacc[nt] = MFMA16(hh, wzl, zacc[nt]);
        short8 wrh = *(const short8*)(smem + L_W + ((((4 + nt) * 2 + kc) * 2 + 0) << 10) + (lane << 4));
        short8 wrl = *(const short8*)(smem + L_W + ((((4 + nt) * 2 + kc) * 2 + 1) << 10) + (lane << 4));
        racc[nt] = MFMA16(hh, wrh, racc[nt]);
        racc[nt] = MFMA16(hl, wrh, racc[nt]);
        racc[nt] = MFMA16(hh, wrl, racc[nt]);
      }
    }

    // ---- sigmoid gates ----
    #pragma unroll
    for (int nt = 0; nt < 4; ++nt)
      #pragma unroll
      for (int reg = 0; reg < 4; ++reg) {
        float zv = zacc[nt][reg] + xreg[reg] * w0z[nt] + bzv[nt];
        zacc[nt][reg] = rcpf(1.0f + __expf(-zv));
        float rv = racc[nt][reg] + xreg[reg] * w0r[nt] + brv[nt];
        racc[nt][reg] = rcpf(1.0f + __expf(-rv));
      }

    // ---- rh = r*h -> RH/RL hi/lo scatter ----
    #pragma unroll
    for (int nt = 0; nt < 4; ++nt) {
      int so = scat_off(nt * 16 + u, g);
      f32x4 rh;
      #pragma unroll
      for (int reg = 0; reg < 4; ++reg) rh[reg] = racc[nt][reg] * hreg[nt][reg];
      scat4_hilo(SCR + R_RH + so, SCR + R_RL + so, rh);
    }

    // ---- attention: lc/gc MFMAs + row-sum MFMAs (all-ones B-frag) ----
    short8 alf0 = *(const short8*)(SCR + R_AL + (lane << 4));
    short8 alf1 = *(const short8*)(SCR + R_AL + 1024 + (lane << 4));
    short8 agf  = *(const short8*)(SCR + R_AG + (lane << 4));
    f32x4 lsum = ZERO4;
    lsum = MFMA16(alf0, ones, lsum);
    lsum = MFMA16(alf1, ones, lsum);
    f32x4 gsum = ZERO4;
    gsum = MFMA16(agf, ones, gsum);
    f32x4 lacc[2], gacc[2];
    #pragma unroll
    for (int nt = 0; nt < 2; ++nt) {
      lacc[nt] = ZERO4;
      gacc[nt] = ZERO4;
      short8 lm0 = *(const short8*)(smem + L_LM + ((0 * 2 + nt) << 10) + (lane << 4));
      short8 lm1 = *(const short8*)(smem + L_LM + ((1 * 2 + nt) << 10) + (lane << 4));
      short8 gm  = *(const short8*)(smem + L_LM + 4096 + (nt << 10) + (lane << 4));
      lacc[nt] = MFMA16(alf0, lm0, lacc[nt]);
      lacc[nt] = MFMA16(alf1, lm1, lacc[nt]);
      gacc[nt] = MFMA16(agf, gm, gacc[nt]);
    }

    // ---- rh reads + Wc MFMA -> hacc ----
    short8 rhh0 = *(const short8*)(SCR + R_RH + (lane << 4));
    short8 rhh1 = *(const short8*)(SCR + R_RH + 1024 + (lane << 4));
    short8 rhl0 = *(const short8*)(SCR + R_RL + (lane << 4));
    short8 rhl1 = *(const short8*)(SCR + R_RL + 1024 + (lane << 4));
    f32x4 hacc[4];
    #pragma unroll
    for (int nt = 0; nt < 4; ++nt) hacc[nt] = ZERO4;
    #pragma unroll
    for (int kc = 0; kc < 2; ++kc) {
      short8 hh = kc ? rhh1 : rhh0;
      short8 hl = kc ? rhl1 : rhl0;
      #pragma unroll
      for (int nt = 0; nt < 4; ++nt) {
        short8 wch = *(const short8*)(smem + L_W + ((((8 + nt) * 2 + kc) * 2 + 0) << 10) + (lane << 4));
        short8 wcl = *(const short8*)(smem + L_W + ((((8 + nt) * 2 + kc) * 2 + 1) << 10) + (lane << 4));
        hacc[nt] = MFMA16(hh, wch, hacc[nt]);
        hacc[nt] = MFMA16(hl, wch, hacc[nt]);
        hacc[nt] = MFMA16(hh, wcl, hacc[nt]);
      }
    }

    // ---- fused = [lc/lsum | gc/gsum] scatter -> FU ----
    float invl[4], invg[4];
    #pragma unroll
    for (int reg = 0; reg < 4; ++reg) {
      invl[reg] = rcpf(lsum[reg]);
      invg[reg] = rcpf(gsum[reg]);
    }
    #pragma unroll
    for (int nt = 0; nt < 2; ++nt) {
      f32x4 lv, gv;
      #pragma unroll
      for (int reg = 0; reg < 4; ++reg) {
        lv[reg] = lacc[nt][reg] * invl[reg];
        gv[reg] = gacc[nt][reg] * invg[reg];
      }
      scat4(SCR + R_FU + scat_off(nt * 16 + u, g), lv);
      scat4(SCR + R_FU + scat_off(32 + nt * 16 + u, g), gv);
    }
    short8 fuf0 = *(const short8*)(SCR + R_FU + (lane << 4));
    short8 fuf1 = *(const short8*)(SCR + R_FU + 1024 + (lane << 4));

    // ---- ctx = fused @ nsw[n] ----
    f32x4 cacc[4];
    #pragma unroll
    for (int nt = 0; nt < 4; ++nt) {
      short8 nf0 = *(const short8*)(SCR + R_NSW + ((0 * 4 + nt) << 10) + (lane << 4));
      short8 nf1 = *(const short8*)(SCR + R_NSW + ((1 * 4 + nt) << 10) + (lane << 4));
      cacc[nt] = ZERO4;
      cacc[nt] = MFMA16(fuf0, nf0, cacc[nt]);
      cacc[nt] = MFMA16(fuf1, nf1, cacc[nt]);
    }

    // ---- combine: tanh + GRU update ----
    #pragma unroll
    for (int nt = 0; nt < 4; ++nt)
      #pragma unroll
      for (int reg = 0; reg < 4; ++reg) {
        float pv = hacc[nt][reg] + cacc[nt][reg] + xreg[reg] * w0c[nt] + bcv[nt];
        float tdenom = rcpf(1.0f + __expf(2.0f * pv));
        float hc = 1.0f - 2.0f * tdenom;               // tanh(pv)
        float zv = zacc[nt][reg];
        hreg[nt][reg] = (1.0f - zv) * hreg[nt][reg] + zv * hc;
      }

    // ---- h_new hi/lo scatter -> HH/HL (serves q-path, head, next step) ----
    #pragma unroll
    for (int nt = 0; nt < 4; ++nt) {
      int so = scat_off(nt * 16 + u, g);
      scat4_hilo(SCR + R_HH + so, SCR + R_HL + so, hreg[nt]);
    }
    short8 nh0 = *(const short8*)(SCR + R_HH + (lane << 4));
    short8 nh1 = *(const short8*)(SCR + R_HH + 1024 + (lane << 4));

    // ---- qnew = h_new @ Wq + bq (Wq frags from LDS) ----
    f32x4 qacc[2];
    #pragma unroll
    for (int nt = 0; nt < 2; ++nt) {
      short8 wq0 = *(const short8*)(smem + L_WQ + ((nt * 2 + 0) << 10) + (lane << 4));
      short8 wq1 = *(const short8*)(smem + L_WQ + ((nt * 2 + 1) << 10) + (lane << 4));
      qacc[nt] = ZERO4;
      qacc[nt] = MFMA16(nh0, wq0, qacc[nt]);
      qacc[nt] = MFMA16(nh1, wq1, qacc[nt]);
      #pragma unroll
      for (int reg = 0; reg < 4; ++reg) qacc[nt][reg] += bqv[nt];
    }
    #pragma unroll
    for (int nt = 0; nt < 2; ++nt)
      scat4(SCR + R_QQ + scat_off(nt * 16 + u, g), qacc[nt]);
    short8 qnf = *(const short8*)(SCR + R_QQ + (lane << 4));
    #pragma unroll
    for (int s = 0; s < 11; ++s) qh[s] = qh[s + 1];
    qh[11] = qnf;

    // ---- decoder head via MFMA: y = h @ Wo + bo (hi/lo split) ----
    if (t >= 12) {
      short8 nhl0 = *(const short8*)(SCR + R_HL + (lane << 4));
      short8 nhl1 = *(const short8*)(SCR + R_HL + 1024 + (lane << 4));
      f32x4 yacc = ZERO4;
      yacc = MFMA16(nh0, woh[0], yacc);
      yacc = MFMA16(nhl0, woh[0], yacc);
      yacc = MFMA16(nh0, wol[0], yacc);
      yacc = MFMA16(nh1, woh[1], yacc);
      yacc = MFMA16(nhl1, woh[1], yacc);
      yacc = MFMA16(nh1, wol[1], yacc);
      #pragma unroll
      for (int reg = 0; reg < 4; ++reg) {
        float yv = yacc[reg] + bov;
        xreg[reg] = yv;
        if (u == 0) {
          int b = hb * 16 + g * 4 + reg;
          out[(b * 12 + (t - 12)) * 512 + n] = yv;
        }
      }
    }
  }
}

// ===========================================================================
extern "C" void kernel_launch(void* const* d_in, const int* in_sizes, int n_in,
                              void* d_out, int out_size, void* d_ws, size_t ws_size,
                              hipStream_t stream) {
  const float* src  = (const float*)d_in[0];
  const float* lmem = (const float*)d_in[1];
  const float* gmem = (const float*)d_in[2];
  const float* Wq   = (const float*)d_in[3];
  const float* bq   = (const float*)d_in[4];
  const float* emb  = (const float*)d_in[5];
  const float* pool = (const float*)d_in[6];
  const float* Wz   = (const float*)d_in[7];
  const float* bz   = (const float*)d_in[8];
  const float* Wr   = (const float*)d_in[9];
  const float* br   = (const float*)d_in[10];
  const float* Wc   = (const float*)d_in[11];
  const float* bc   = (const float*)d_in[12];
  const float* Wo   = (const float*)d_in[13];
  const float* bo   = (const float*)d_in[14];
  float* out = (float*)d_out;
  unsigned short* ws = (unsigned short*)d_ws;

  dyna_prep<<<260, 256, 0, stream>>>(lmem, gmem, Wq, Wz, Wr, Wc, ws);

  (void)hipFuncSetAttribute((const void*)dyna_main,
                            hipFuncAttributeMaxDynamicSharedMemorySize,
                            SMEM_BYTES);
  dyna_main<<<256, 256, SMEM_BYTES, stream>>>(src, emb, pool, bq, Wz, bz, Wr, br,
                                              Wc, bc, Wo, bo, ws, out);
}

// Round 9
// 197.549 us; speedup vs baseline: 1.1043x; 1.1043x over previous
//
#include <hip/hip_runtime.h>

// ---------------------------------------------------------------------------
// H_DYNA: fused 24-step recurrent memory-attention GRU on MI355X (gfx950).
// R8 = R6 structure (full 72-MFMA score block per step, NO cross-step
// pipelining -- that was R7's 28% regression) + two kept R7 wins:
//  - softmax row-sums via MFMA with all-ones B-frag (shuffle trees removed
//    from the exp->scatter->gates critical path)
//  - decoder head y = h@Wo via MFMA broadcast-Wo frags (hi/lo split)
// ---------------------------------------------------------------------------

typedef short short8 __attribute__((ext_vector_type(8)));   // 8 x bf16 bits
typedef float f32x4 __attribute__((ext_vector_type(4)));

#define DEV static __device__ __forceinline__

DEV unsigned short f2bf(float f) {
  union { float f; unsigned u; } v; v.f = f;
  unsigned r = v.u + 0x7FFFu + ((v.u >> 16) & 1u);   // RNE
  return (unsigned short)(r >> 16);
}
DEV float bf2f(unsigned short b) {
  union { unsigned u; float f; } v; v.u = ((unsigned)b) << 16;
  return v.f;
}
DEV unsigned cvtpk(float a, float b) {                // packed RNE f32->bf16 x2
  unsigned r;
  asm("v_cvt_pk_bf16_f32 %0, %1, %2" : "=v"(r) : "v"(a), "v"(b));
  return r;
}
DEV float rcpf(float x) { return __builtin_amdgcn_rcpf(x); }

// ---- ws layout (ushort units) ----
#define WG_OFF  36864   // mem frags: 72 frags * 512 before this
#define WQ_OFF  61440   // gate-W frags: 48 * 512 (hi/lo interleaved)
#define LM_OFF  63488   // Wq frags: 4 * 512
#define GM_OFF  65536   // lmean frags: 4 * 512
#define WS_TOT  66560   // gmean frags: 2 * 512

// ---- LDS layout (bytes) ----
#define L_W     0             // 48 gate-W frags (fid order), 49152 B
#define L_WQ    49152         // 4 Wq frags
#define L_LM    53248         // lmean 4 + gmean 2 frags
#define L_SCR   59392         // per-wave scratch
#define SCR_STRIDE 21504
#define SMEM_BYTES 145408     // 59392 + 4*21504

// per-wave scratch regions
#define R_AL 0
#define R_AG 2048
#define R_FU 3072
#define R_HH 5120
#define R_HL 7168
#define R_RH 9216
#define R_RL 11264
#define R_NSW 13312           // 8 KB: nsw B-frags (per-wave copy)
#define R_QQ 0                // reuse AL after its reads

#define MFMA16(a, b, c) __builtin_amdgcn_mfma_f32_16x16x32_bf16((a), (b), (c), 0, 0, 0)

// A-frag scatter address for element (row = 4g+reg via +reg*16, k = col)
DEV int scat_off(int col, int g) {
  int kp = col & 31;
  return ((col >> 5) << 10) + ((kp >> 3) << 8) + (g << 6) + ((kp & 7) << 1);
}
DEV void scat4(char* p, f32x4 v) {        // 4 C-regs -> bf16 A-layout
  unsigned p0 = cvtpk(v[0], v[1]), p1 = cvtpk(v[2], v[3]);
  *(unsigned short*)(p)      = (unsigned short)p0;
  *(unsigned short*)(p + 16) = (unsigned short)(p0 >> 16);
  *(unsigned short*)(p + 32) = (unsigned short)p1;
  *(unsigned short*)(p + 48) = (unsigned short)(p1 >> 16);
}
DEV void scat4_hilo(char* ph, char* pl, f32x4 v) {   // hi/lo split scatter
  unsigned p0 = cvtpk(v[0], v[1]), p1 = cvtpk(v[2], v[3]);
  float h0 = __uint_as_float(p0 << 16), h1 = __uint_as_float(p0 & 0xFFFF0000u);
  float h2 = __uint_as_float(p1 << 16), h3 = __uint_as_float(p1 & 0xFFFF0000u);
  unsigned q0 = cvtpk(v[0] - h0, v[1] - h1), q1 = cvtpk(v[2] - h2, v[3] - h3);
  *(unsigned short*)(ph)      = (unsigned short)p0;
  *(unsigned short*)(ph + 16) = (unsigned short)(p0 >> 16);
  *(unsigned short*)(ph + 32) = (unsigned short)p1;
  *(unsigned short*)(ph + 48) = (unsigned short)(p1 >> 16);
  *(unsigned short*)(pl)      = (unsigned short)q0;
  *(unsigned short*)(pl + 16) = (unsigned short)(q0 >> 16);
  *(unsigned short*)(pl + 32) = (unsigned short)q1;
  *(unsigned short*)(pl + 48) = (unsigned short)(q1 >> 16);
}

// ===========================================================================
// Prep: pack memory / weight matrices into MFMA B-fragment order (bf16).
// (unchanged)
// ===========================================================================
__global__ __launch_bounds__(256, 1) void dyna_prep(
    const float* __restrict__ lmem, const float* __restrict__ gmem,
    const float* __restrict__ Wq, const float* __restrict__ Wz,
    const float* __restrict__ Wr, const float* __restrict__ Wc,
    unsigned short* __restrict__ ws)
{
  int i = blockIdx.x * 256 + threadIdx.x;
  if (i >= WS_TOT) return;

  if (i < WG_OFF) {                       // score-memory frags: [s 0..11][nt 0..5]
    int f = i >> 9, r = i & 511, lane = r >> 3, j = r & 7;
    int g = lane >> 4, u = lane & 15;
    int s = f / 6, nt = f % 6;
    int m = nt * 16 + u, p = g * 8 + j;
    float v = (m < 64) ? lmem[(m * 12 + s) * 32 + p]
                       : gmem[((m - 64) * 12 + s) * 32 + p];
    ws[i] = f2bf(v);
  } else if (i < WQ_OFF) {                // gate W frags: fid=((gate*4+nt)*2+kc)*2+hl
    int t = i - WG_OFF;
    int f = t >> 9, r = t & 511, lane = r >> 3, j = r & 7;
    int g = lane >> 4, u = lane & 15;
    int hl = f & 1, kc = (f >> 1) & 1, nt = (f >> 2) & 3, gate = f >> 4;
    int k = kc * 32 + g * 8 + j, col = nt * 16 + u;
    const float* W = (gate == 0) ? Wz : (gate == 1) ? Wr : Wc;
    float w = W[(1 + k) * 64 + col];
    if (hl) { float hi = bf2f(f2bf(w)); ws[i] = f2bf(w - hi); }
    else ws[i] = f2bf(w);
  } else if (i < LM_OFF) {                // Wq frags: fid = nt*2+kc
    int t = i - WQ_OFF;
    int f = t >> 9, r = t & 511, lane = r >> 3, j = r & 7;
    int g = lane >> 4, u = lane & 15;
    int kc = f & 1, nt = f >> 1;
    int k = kc * 32 + g * 8 + j, col = nt * 16 + u;
    ws[i] = f2bf(Wq[k * 32 + col]);
  } else if (i < GM_OFF) {                // lmean frags: fid = kc*2+nt
    int t = i - LM_OFF;
    int f = t >> 9, r = t & 511, lane = r >> 3, j = r & 7;
    int g = lane >> 4, u = lane & 15;
    int kc = f >> 1, nt = f & 1;
    int k = kc * 32 + g * 8 + j, p = nt * 16 + u;
    float s = 0.f;
    for (int ss = 0; ss < 12; ++ss) s += lmem[(k * 12 + ss) * 32 + p];
    ws[i] = f2bf(s * (1.0f / 12.0f));
  } else {                                // gmean frags: fid = nt
    int t = i - GM_OFF;
    int f = t >> 9, r = t & 511, lane = r >> 3, j = r & 7;
    int g = lane >> 4, u = lane & 15;
    int nt = f;
    int k = g * 8 + j, p = nt * 16 + u;
    float s = 0.f;
    for (int ss = 0; ss < 12; ++ss) s += gmem[(k * 12 + ss) * 32 + p];
    ws[i] = f2bf(s * (1.0f / 12.0f));
  }
}

// ===========================================================================
// Main fused kernel. 256 blocks * 256 thr. Block = nodes {2B, 2B+1};
// wave w: node 2B+(w>>1), batch half (w&1), rows = hb*16 + 4g+reg.
// ===========================================================================
__global__ __launch_bounds__(256, 1) void dyna_main(
    const float* __restrict__ src, const float* __restrict__ emb,
    const float* __restrict__ pool, const float* __restrict__ bq,
    const float* __restrict__ Wz, const float* __restrict__ bz,
    const float* __restrict__ Wr, const float* __restrict__ br,
    const float* __restrict__ Wc, const float* __restrict__ bc,
    const float* __restrict__ Wo, const float* __restrict__ bo,
    const unsigned short* __restrict__ ws, float* __restrict__ out)
{
  extern __shared__ char smem[];
  const int tid = threadIdx.x;
  const int lane = tid & 63, wid = tid >> 6;
  const int g = lane >> 4, u = lane & 15;
  const int n = blockIdx.x * 2 + (wid >> 1);
  const int hb = wid & 1;
  const f32x4 ZERO4 = {0.f, 0.f, 0.f, 0.f};

  // ---- stage W (48) + Wq (4) + lm/gm (6) frags: ws is contiguous here ----
  {
    const short8* s8 = (const short8*)ws;
    short8* d8 = (short8*)smem;
    for (int i = tid; i < 3712; i += 256) d8[i] = s8[4608 + i];  // 4608 = WG_OFF/8
  }

  // ---- 72 score-memory B-frags -> registers (one-time global load) ----
  short8 marr[72];
  #pragma unroll
  for (int f = 0; f < 72; ++f)
    marr[f] = *(const short8*)(ws + (f << 9) + lane * 8);

  char* SCR = smem + L_SCR + wid * SCR_STRIDE;

  // ---- nsw[n] = emb[n] @ pool, built as B-frags, stored in per-wave LDS ----
  #pragma unroll
  for (int kc = 0; kc < 2; ++kc)
    #pragma unroll
    for (int nt = 0; nt < 4; ++nt) {
      short8 v;
      #pragma unroll
      for (int j = 0; j < 8; ++j) {
        int k = kc * 32 + g * 8 + j, col = nt * 16 + u;
        float s = 0.f;
        #pragma unroll
        for (int d = 0; d < 10; ++d)
          s += emb[n * 10 + d] * pool[(d * 64 + k) * 64 + col];
        v[j] = (short)f2bf(s);
      }
      *(short8*)(SCR + R_NSW + ((kc * 4 + nt) << 10) + (lane << 4)) = v;
    }

  // ---- special B-frags: all-ones (row-sum) + broadcast Wo (hi/lo) ----
  short8 ones, woh[2], wol[2];
  #pragma unroll
  for (int j = 0; j < 8; ++j) ones[j] = (short)0x3F80;
  #pragma unroll
  for (int kc = 0; kc < 2; ++kc)
    #pragma unroll
    for (int j = 0; j < 8; ++j) {
      float w = Wo[kc * 32 + g * 8 + j];
      unsigned short hi = f2bf(w);
      woh[kc][j] = (short)hi;
      wol[kc][j] = (short)f2bf(w - bf2f(hi));
    }

  // ---- per-lane constants ----
  float w0z[4], w0r[4], w0c[4], bzv[4], brv[4], bcv[4], bqv[2];
  #pragma unroll
  for (int nt = 0; nt < 4; ++nt) {
    int col = nt * 16 + u;
    w0z[nt] = Wz[col]; w0r[nt] = Wr[col]; w0c[nt] = Wc[col];
    bzv[nt] = bz[col]; brv[nt] = br[col]; bcv[nt] = bc[col];
  }
  bqv[0] = bq[u]; bqv[1] = bq[16 + u];
  const float bov = bo[0];

  // ---- persistent per-row state ----
  short8 qh[12];
  {
    short8 qi;
    #pragma unroll
    for (int j = 0; j < 8; ++j) qi[j] = (short)f2bf(bq[g * 8 + j]);
    #pragma unroll
    for (int s = 0; s < 12; ++s) qh[s] = qi;
  }
  f32x4 hreg[4];
  #pragma unroll
  for (int nt = 0; nt < 4; ++nt) hreg[nt] = ZERO4;
  float xreg[4] = {0.f, 0.f, 0.f, 0.f};

  // initial h=0 hi/lo scatter (serves step 0's gate reads)
  #pragma unroll
  for (int nt = 0; nt < 4; ++nt) {
    int so = scat_off(nt * 16 + u, g);
    scat4_hilo(SCR + R_HH + so, SCR + R_HL + so, hreg[nt]);
  }

  __syncthreads();    // staged shared frags visible; the only barrier

  for (int t = 0; t < 24; ++t) {
    // ---- x input (global latency hides under score MFMAs) ----
    if (t <= 12) {
      int tt = t < 12 ? t : 11;
      #pragma unroll
      for (int reg = 0; reg < 4; ++reg) {
        int b = hb * 16 + g * 4 + reg;
        xreg[reg] = src[(b * 12 + tt) * 512 + n];
      }
    }

    // ---- h_prev frag reads issued early (latency under score loop) ----
    short8 hhi0 = *(const short8*)(SCR + R_HH + (lane << 4));
    short8 hhi1 = *(const short8*)(SCR + R_HH + 1024 + (lane << 4));
    short8 hlo0 = *(const short8*)(SCR + R_HL + (lane << 4));
    short8 hlo1 = *(const short8*)(SCR + R_HL + 1024 + (lane << 4));

    // ---- scores: pure-register MFMA, 72 ops ----
    f32x4 sacc[6];
    #pragma unroll
    for (int nt = 0; nt < 6; ++nt) sacc[nt] = ZERO4;
    __builtin_amdgcn_s_setprio(1);
    #pragma unroll
    for (int s = 0; s < 12; ++s) {
      #pragma unroll
      for (int nt = 0; nt < 6; ++nt)
        sacc[nt] = MFMA16(qh[s], marr[s * 6 + nt], sacc[nt]);
    }
    __builtin_amdgcn_s_setprio(0);

    // ---- e = exp(score); scatter unnormalized e -> AL / AG (no shuffles;
    //      row-sums come later via all-ones MFMA) ----
    #pragma unroll
    for (int nt = 0; nt < 6; ++nt)
      #pragma unroll
      for (int reg = 0; reg < 4; ++reg)
        sacc[nt][reg] = __expf(sacc[nt][reg]);
    #pragma unroll
    for (int nt = 0; nt < 4; ++nt)
      scat4(SCR + R_AL + scat_off(nt * 16 + u, g), sacc[nt]);
    #pragma unroll
    for (int nt = 0; nt < 2; ++nt)
      scat4(SCR + R_AG + scat_off(nt * 16 + u, g), sacc[4 + nt]);

    // ---- z, r gates: hi/lo split MFMA (W hi+lo from LDS) ----
    f32x4 zacc[4], racc[4];
    #pragma unroll
    for (int nt = 0; nt < 4; ++nt) {
      zacc[nt] = ZERO4;
      racc[nt] = ZERO4;
    }
    #pragma unroll
    for (int kc = 0; kc < 2; ++kc) {
      short8 hh = kc ? hhi1 : hhi0;
      short8 hl = kc ? hlo1 : hlo0;
      #pragma unroll
      for (int nt = 0; nt < 4; ++nt) {
        short8 wzh = *(const short8*)(smem + L_W + ((((0 + nt) * 2 + kc) * 2 + 0) << 10) + (lane << 4));
        short8 wzl = *(const short8*)(smem + L_W + ((((0 + nt) * 2 + kc) * 2 + 1) << 10) + (lane << 4));
        zacc[nt] = MFMA16(hh, wzh, zacc[nt]);
        zacc[nt] = MFMA16(hl, wzh, zacc[nt]);
        zacc[nt] = MFMA16(hh, wzl, zacc[nt]);
        short8 wrh = *(const short8*)(smem + L_W + ((((4 + nt) * 2 + kc) * 2 + 0) << 10) + (lane << 4));
        short8 wrl = *(const short8*)(smem + L_W + ((((4 + nt) * 2 + kc) * 2 + 1) << 10) + (lane << 4));
        racc[nt] = MFMA16(hh, wrh, racc[nt]);
        racc[nt] = MFMA16(hl, wrh, racc[nt]);
        racc[nt] = MFMA16(hh, wrl, racc[nt]);
      }
    }

    // ---- sigmoid gates ----
    #pragma unroll
    for (int nt = 0; nt < 4; ++nt)
      #pragma unroll
      for (int reg = 0; reg < 4; ++reg) {
        float zv = zacc[nt][reg] + xreg[reg] * w0z[nt] + bzv[nt];
        zacc[nt][reg] = rcpf(1.0f + __expf(-zv));
        float rv = racc[nt][reg] + xreg[reg] * w0r[nt] + brv[nt];
        racc[nt][reg] = rcpf(1.0f + __expf(-rv));
      }

    // ---- rh = r*h -> RH/RL hi/lo scatter ----
    #pragma unroll
    for (int nt = 0; nt < 4; ++nt) {
      int so = scat_off(nt * 16 + u, g);
      f32x4 rh;
      #pragma unroll
      for (int reg = 0; reg < 4; ++reg) rh[reg] = racc[nt][reg] * hreg[nt][reg];
      scat4_hilo(SCR + R_RH + so, SCR + R_RL + so, rh);
    }

    // ---- attention: lc/gc MFMAs + row-sum MFMAs (all-ones B-frag) ----
    short8 alf0 = *(const short8*)(SCR + R_AL + (lane << 4));
    short8 alf1 = *(const short8*)(SCR + R_AL + 1024 + (lane << 4));
    short8 agf  = *(const short8*)(SCR + R_AG + (lane << 4));
    f32x4 lsum = ZERO4;
    lsum = MFMA16(alf0, ones, lsum);
    lsum = MFMA16(alf1, ones, lsum);
    f32x4 gsum = ZERO4;
    gsum = MFMA16(agf, ones, gsum);
    f32x4 lacc[2], gacc[2];
    #pragma unroll
    for (int nt = 0; nt < 2; ++nt) {
      lacc[nt] = ZERO4;
      gacc[nt] = ZERO4;
      short8 lm0 = *(const short8*)(smem + L_LM + ((0 * 2 + nt) << 10) + (lane << 4));
      short8 lm1 = *(const short8*)(smem + L_LM + ((1 * 2 + nt) << 10) + (lane << 4));
      short8 gm  = *(const short8*)(smem + L_LM + 4096 + (nt << 10) + (lane << 4));
      lacc[nt] = MFMA16(alf0, lm0, lacc[nt]);
      lacc[nt] = MFMA16(alf1, lm1, lacc[nt]);
      gacc[nt] = MFMA16(agf, gm, gacc[nt]);
    }

    // ---- rh reads + Wc MFMA -> hacc ----
    short8 rhh0 = *(const short8*)(SCR + R_RH + (lane << 4));
    short8 rhh1 = *(const short8*)(SCR + R_RH + 1024 + (lane << 4));
    short8 rhl0 = *(const short8*)(SCR + R_RL + (lane << 4));
    short8 rhl1 = *(const short8*)(SCR + R_RL + 1024 + (lane << 4));
    f32x4 hacc[4];
    #pragma unroll
    for (int nt = 0; nt < 4; ++nt) hacc[nt] = ZERO4;
    #pragma unroll
    for (int kc = 0; kc < 2; ++kc) {
      short8 hh = kc ? rhh1 : rhh0;
      short8 hl = kc ? rhl1 : rhl0;
      #pragma unroll
      for (int nt = 0; nt < 4; ++nt) {
        short8 wch = *(const short8*)(smem + L_W + ((((8 + nt) * 2 + kc) * 2 + 0) << 10) + (lane << 4));
        short8 wcl = *(const short8*)(smem + L_W + ((((8 + nt) * 2 + kc) * 2 + 1) << 10) + (lane << 4));
        hacc[nt] = MFMA16(hh, wch, hacc[nt]);
        hacc[nt] = MFMA16(hl, wch, hacc[nt]);
        hacc[nt] = MFMA16(hh, wcl, hacc[nt]);
      }
    }

    // ---- fused = [lc/lsum | gc/gsum] scatter -> FU ----
    float invl[4], invg[4];
    #pragma unroll
    for (int reg = 0; reg < 4; ++reg) {
      invl[reg] = rcpf(lsum[reg]);
      invg[reg] = rcpf(gsum[reg]);
    }
    #pragma unroll
    for (int nt = 0; nt < 2; ++nt) {
      f32x4 lv, gv;
      #pragma unroll
      for (int reg = 0; reg < 4; ++reg) {
        lv[reg] = lacc[nt][reg] * invl[reg];
        gv[reg] = gacc[nt][reg] * invg[reg];
      }
      scat4(SCR + R_FU + scat_off(nt * 16 + u, g), lv);
      scat4(SCR + R_FU + scat_off(32 + nt * 16 + u, g), gv);
    }
    short8 fuf0 = *(const short8*)(SCR + R_FU + (lane << 4));
    short8 fuf1 = *(const short8*)(SCR + R_FU + 1024 + (lane << 4));

    // ---- ctx = fused @ nsw[n] ----
    f32x4 cacc[4];
    #pragma unroll
    for (int nt = 0; nt < 4; ++nt) {
      short8 nf0 = *(const short8*)(SCR + R_NSW + ((0 * 4 + nt) << 10) + (lane << 4));
      short8 nf1 = *(const short8*)(SCR + R_NSW + ((1 * 4 + nt) << 10) + (lane << 4));
      cacc[nt] = ZERO4;
      cacc[nt] = MFMA16(fuf0, nf0, cacc[nt]);
      cacc[nt] = MFMA16(fuf1, nf1, cacc[nt]);
    }

    // ---- combine: tanh + GRU update ----
    #pragma unroll
    for (int nt = 0; nt < 4; ++nt)
      #pragma unroll
      for (int reg = 0; reg < 4; ++reg) {
        float pv = hacc[nt][reg] + cacc[nt][reg] + xreg[reg] * w0c[nt] + bcv[nt];
        float tdenom = rcpf(1.0f + __expf(2.0f * pv));
        float hc = 1.0f - 2.0f * tdenom;               // tanh(pv)
        float zv = zacc[nt][reg];
        hreg[nt][reg] = (1.0f - zv) * hreg[nt][reg] + zv * hc;
      }

    // ---- h_new hi/lo scatter -> HH/HL (serves q-path, head, next step) ----
    #pragma unroll
    for (int nt = 0; nt < 4; ++nt) {
      int so = scat_off(nt * 16 + u, g);
      scat4_hilo(SCR + R_HH + so, SCR + R_HL + so, hreg[nt]);
    }
    short8 nh0 = *(const short8*)(SCR + R_HH + (lane << 4));
    short8 nh1 = *(const short8*)(SCR + R_HH + 1024 + (lane << 4));

    // ---- qnew = h_new @ Wq + bq (Wq frags from LDS) ----
    f32x4 qacc[2];
    #pragma unroll
    for (int nt = 0; nt < 2; ++nt) {
      short8 wq0 = *(const short8*)(smem + L_WQ + ((nt * 2 + 0) << 10) + (lane << 4));
      short8 wq1 = *(const short8*)(smem + L_WQ + ((nt * 2 + 1) << 10) + (lane << 4));
      qacc[nt] = ZERO4;
      qacc[nt] = MFMA16(nh0, wq0, qacc[nt]);
      qacc[nt] = MFMA16(nh1, wq1, qacc[nt]);
      #pragma unroll
      for (int reg = 0; reg < 4; ++reg) qacc[nt][reg] += bqv[nt];
    }
    #pragma unroll
    for (int nt = 0; nt < 2; ++nt)
      scat4(SCR + R_QQ + scat_off(nt * 16 + u, g), qacc[nt]);
    short8 qnf = *(const short8*)(SCR + R_QQ + (lane << 4));
    #pragma unroll
    for (int s = 0; s < 11; ++s) qh[s] = qh[s + 1];
    qh[11] = qnf;

    // ---- decoder head via MFMA: y = h @ Wo + bo (hi/lo split) ----
    if (t >= 12) {
      short8 nhl0 = *(const short8*)(SCR + R_HL + (lane << 4));
      short8 nhl1 = *(const short8*)(SCR + R_HL + 1024 + (lane << 4));
      f32x4 yacc = ZERO4;
      yacc = MFMA16(nh0, woh[0], yacc);
      yacc = MFMA16(nhl0, woh[0], yacc);
      yacc = MFMA16(nh0, wol[0], yacc);
      yacc = MFMA16(nh1, woh[1], yacc);
      yacc = MFMA16(nhl1, woh[1], yacc);
      yacc = MFMA16(nh1, wol[1], yacc);
      #pragma unroll
      for (int reg = 0; reg < 4; ++reg) {
        float yv = yacc[reg] + bov;
        xreg[reg] = yv;
        if (u == 0) {
          int b = hb * 16 + g * 4 + reg;
          out[(b * 12 + (t - 12)) * 512 + n] = yv;
        }
      }
    }
  }
}

// ===========================================================================
extern "C" void kernel_launch(void* const* d_in, const int* in_sizes, int n_in,
                              void* d_out, int out_size, void* d_ws, size_t ws_size,
                              hipStream_t stream) {
  const float* src  = (const float*)d_in[0];
  const float* lmem = (const float*)d_in[1];
  const float* gmem = (const float*)d_in[2];
  const float* Wq   = (const float*)d_in[3];
  const float* bq   = (const float*)d_in[4];
  const float* emb  = (const float*)d_in[5];
  const float* pool = (const float*)d_in[6];
  const float* Wz   = (const float*)d_in[7];
  const float* bz   = (const float*)d_in[8];
  const float* Wr   = (const float*)d_in[9];
  const float* br   = (const float*)d_in[10];
  const float* Wc   = (const float*)d_in[11];
  const float* bc   = (const float*)d_in[12];
  const float* Wo   = (const float*)d_in[13];
  const float* bo   = (const float*)d_in[14];
  float* out = (float*)d_out;
  unsigned short* ws = (unsigned short*)d_ws;

  dyna_prep<<<260, 256, 0, stream>>>(lmem, gmem, Wq, Wz, Wr, Wc, ws);

  (void)hipFuncSetAttribute((const void*)dyna_main,
                            hipFuncAttributeMaxDynamicSharedMemorySize,
                            SMEM_BYTES);
  dyna_main<<<256, 256, SMEM_BYTES, stream>>>(src, emb, pool, bq, Wz, bz, Wr, br,
                                              Wc, bc, Wo, bo, ws, out);
}